// Round 4
// baseline (414.773 us; speedup 1.0000x reference)
//
#include <hip/hip_runtime.h>
#include <stdint.h>

// DiffLogic: 3-layer differentiable logic network.
// Round 10: break the gather latency chain. R9 counters (VALUBusy 18.8%,
// occ 27%, HBM 3.6%, L2 rate ~5 TB/s vs 34.5 ceiling) = latency-bound:
// each unroll-group serialized ds_read(idx) -> readfirstlane -> gather ->
// vmcnt -> compute. Fix: explicit depth-2 software pipeline -- gate u+1's
// 8 gathers are in flight while gate u computes; u+2's issue after.
// Gate data in fully-unrolled register structs (all compile-time indexed,
// no scratch). Live set ~100 VGPR, under the 128 cap of (512,4):
// deliberately between R8's spill (cap 64) and R9's under-pipelined 44.

#define BATCH   256
#define IN_DIM  1024
#define WIDTH   64000
#define NGROUP  10
#define GSIZE   6400      // WIDTH / NGROUP
#define TAU     30.0f
#define NWAVE   8         // waves per block (512 threads)
#define GPW     8         // gates per wave
#define GPB     (NWAVE*GPW)   // 64 gates/block; 6400 % 64 == 0
#define NBLK    (WIDTH/GPB)   // 1000

typedef unsigned short ushort_t;

static __device__ __forceinline__ float bf2f(ushort_t s) {
    return __uint_as_float((uint32_t)s << 16);
}
static __device__ __forceinline__ ushort_t f2bf(float f) {   // RNE
    uint32_t u = __float_as_uint(f);
    return (ushort_t)((u + 0x7fffu + ((u >> 16) & 1u)) >> 16);
}
// h = c0 + c1*a + c2*b + c3*(a*b) = b*(c3*a+c2) + (c1*a+c0)  -- 3 FMA/elem
static __device__ __forceinline__ float gate1(float4 c, float a, float b) {
    return fmaf(b, fmaf(c.w, a, c.z), fmaf(c.y, a, c.x));
}
static __device__ __forceinline__ float4 gate4(float4 c, float4 a, float4 b) {
    float4 r;
    r.x = gate1(c, a.x, b.x);
    r.y = gate1(c, a.y, b.y);
    r.z = gate1(c, a.z, b.z);
    r.w = gate1(c, a.w, b.w);
    return r;
}
static __device__ __forceinline__ float4 up4(ushort4 s) {
    return make_float4(bf2f(s.x), bf2f(s.y), bf2f(s.z), bf2f(s.w));
}

// ---------------------------------------------------------------- transpose
// x:(256,1024) f32 row-major -> xT:(1024,256) bf16
__global__ __launch_bounds__(256) void transpose_kernel(
    const float* __restrict__ x, ushort_t* __restrict__ xT)
{
    __shared__ float tile[64][65];
    const int c0 = (blockIdx.x & 15) * 64;
    const int b0 = (blockIdx.x >> 4) * 64;
    const int lt = threadIdx.x & 63;
    const int wt = threadIdx.x >> 6;
    for (int r = wt; r < 64; r += 4)
        tile[r][lt] = x[(b0 + r) * IN_DIM + c0 + lt];
    __syncthreads();
    for (int r = wt; r < 64; r += 4)
        xT[(c0 + r) * BATCH + b0 + lt] = f2bf(tile[lt][r]);
}

// ---------------------------------------------------------------- softmax coef
static __device__ __forceinline__ float4 softmax_coef(const float* __restrict__ w)
{
    const float4* w4 = (const float4*)w;
    float4 q0 = w4[0], q1 = w4[1], q2 = w4[2], q3 = w4[3];
    float p[16] = {q0.x,q0.y,q0.z,q0.w, q1.x,q1.y,q1.z,q1.w,
                   q2.x,q2.y,q2.z,q2.w, q3.x,q3.y,q3.z,q3.w};
    float m = p[0];
    #pragma unroll
    for (int i = 1; i < 16; ++i) m = fmaxf(m, p[i]);
    float s = 0.f;
    #pragma unroll
    for (int i = 0; i < 16; ++i) { p[i] = __expf(p[i] - m); s += p[i]; }
    const float inv = 1.0f / s;
    float c0 = (p[8]+p[9]+p[10]+p[11]+p[12]+p[13]+p[14]+p[15]) * inv;
    float c1 = (p[2]+p[3]+p[6]+p[7] - p[8]-p[9]-p[12]-p[13]) * inv;
    float c2 = (p[4]+p[5]+p[6]+p[7] - p[8]-p[9]-p[10]-p[11]) * inv;
    float c3 = (p[1]-p[2]-p[4]-2.f*p[6]-p[7]+p[8]+2.f*p[9]+p[11]+p[13]-p[14]) * inv;
    return make_float4(c0, c1, c2, c3);
}

// ---------------------------------------------------------------- tree prep
__global__ __launch_bounds__(256) void prep_kernel(
    const float* __restrict__ w1, const float* __restrict__ w2,
    const float* __restrict__ w3,
    const int* __restrict__ ia1, const int* __restrict__ ib1,
    const int* __restrict__ ia2, const int* __restrict__ ib2,
    const int* __restrict__ ia3, const int* __restrict__ ib3,
    int* __restrict__ leaf,        // [WIDTH][8]
    float4* __restrict__ pc)       // [WIDTH][7]
{
    const int j = blockIdx.x * 256 + threadIdx.x;
    if (j >= WIDTH) return;

    const int pa = ia3[j], pb = ib3[j];
    const int qaa = ia2[pa], qab = ib2[pa];
    const int qba = ia2[pb], qbb = ib2[pb];

    int* L = leaf + (size_t)j * 8;
    L[0] = ia1[qaa]; L[1] = ib1[qaa];
    L[2] = ia1[qab]; L[3] = ib1[qab];
    L[4] = ia1[qba]; L[5] = ib1[qba];
    L[6] = ia1[qbb]; L[7] = ib1[qbb];

    float4* P = pc + (size_t)j * 7;
    P[0] = softmax_coef(w1 + (size_t)qaa * 16);
    P[1] = softmax_coef(w1 + (size_t)qab * 16);
    P[2] = softmax_coef(w1 + (size_t)qba * 16);
    P[3] = softmax_coef(w1 + (size_t)qbb * 16);
    P[4] = softmax_coef(w2 + (size_t)pa * 16);
    P[5] = softmax_coef(w2 + (size_t)pb * 16);
    P[6] = softmax_coef(w3 + (size_t)j * 16);
}

// ---------------------------------------------------------------- fused net
// One gate's 8 leaf columns, fully register-resident (compile-time indexed).
struct G8 { ushort4 v[8]; };

static __device__ __forceinline__ G8 load_gate(
    const ushort_t* __restrict__ xT, const int* sleaf, int g, int lane)
{
    G8 r;
    #pragma unroll
    for (int k = 0; k < 8; ++k) {
        const int col = __builtin_amdgcn_readfirstlane(sleaf[g * 8 + k]);
        r.v[k] = ((const ushort4*)(xT + (size_t)col * BATCH))[lane];
    }
    return r;
}

static __device__ __forceinline__ float4 comp_gate(
    const G8& d, const float4* spc, int g)
{
    const float4 C1aa = spc[g*7 + 0];
    const float4 C1ab = spc[g*7 + 1];
    const float4 C1ba = spc[g*7 + 2];
    const float4 C1bb = spc[g*7 + 3];
    const float4 C2a  = spc[g*7 + 4];
    const float4 C2b  = spc[g*7 + 5];
    const float4 C3c  = spc[g*7 + 6];

    const float4 haa = gate4(C1aa, up4(d.v[0]), up4(d.v[1]));
    const float4 hab = gate4(C1ab, up4(d.v[2]), up4(d.v[3]));
    const float4 hba = gate4(C1ba, up4(d.v[4]), up4(d.v[5]));
    const float4 hbb = gate4(C1bb, up4(d.v[6]), up4(d.v[7]));
    const float4 h2a = gate4(C2a, haa, hab);
    const float4 h2b = gate4(C2b, hba, hbb);
    return gate4(C3c, h2a, h2b);
}

__global__ __launch_bounds__(512, 4) void fused_kernel(
    const ushort_t* __restrict__ xT,
    const int*      __restrict__ leaf,
    const float4*   __restrict__ pc,
    float*          __restrict__ red_out)
{
    __shared__ int    sleaf[GPB * 8];        // 2 KB
    __shared__ float4 spc[GPB * 7];          // 7 KB
    __shared__ float4 sred[NWAVE][64];       // 8 KB

    const int tid = threadIdx.x;

    // ---- coalesced metadata stage (block's spans are contiguous)
    sleaf[tid] = leaf[(size_t)blockIdx.x * (GPB * 8) + tid];      // 512 x 4B
    if (tid < GPB * 7)
        spc[tid] = pc[(size_t)blockIdx.x * (GPB * 7) + tid];      // 448 x 16B
    __syncthreads();

    const int lane = tid & 63;
    const int wave = tid >> 6;
    const int gbase = wave * GPW;

    // ---- depth-2 software pipeline: loads for gate u+1 in flight while
    //      gate u computes; u+2 issued right after.
    G8 cur = load_gate(xT, sleaf, gbase + 0, lane);
    G8 nxt = load_gate(xT, sleaf, gbase + 1, lane);

    float4 acc = make_float4(0.f, 0.f, 0.f, 0.f);

    #pragma unroll
    for (int u = 0; u < GPW; ++u) {
        const float4 h = comp_gate(cur, spc, gbase + u);
        acc.x += h.x; acc.y += h.y; acc.z += h.z; acc.w += h.w;
        cur = nxt;
        if (u + 2 < GPW)
            nxt = load_gate(xT, sleaf, gbase + u + 2, lane);
    }

    // ---- block reduction + grouped atomic add
    sred[wave][lane] = acc;
    __syncthreads();
    if (wave == 0) {
        float4 t = sred[0][lane];
        #pragma unroll
        for (int w = 1; w < NWAVE; ++w) {
            float4 q = sred[w][lane];
            t.x += q.x; t.y += q.y; t.z += q.z; t.w += q.w;
        }
        const float sc = 1.0f / TAU;
        const int grp = (blockIdx.x * GPB) / GSIZE;
        const int b0 = lane * 4;
        atomicAdd(&red_out[(b0 + 0) * NGROUP + grp], t.x * sc);
        atomicAdd(&red_out[(b0 + 1) * NGROUP + grp], t.y * sc);
        atomicAdd(&red_out[(b0 + 2) * NGROUP + grp], t.z * sc);
        atomicAdd(&red_out[(b0 + 3) * NGROUP + grp], t.w * sc);
    }
}

// ---------------------------------------------------------------- launch
extern "C" void kernel_launch(void* const* d_in, const int* in_sizes, int n_in,
                              void* d_out, int out_size, void* d_ws, size_t ws_size,
                              hipStream_t stream)
{
    const float* x   = (const float*)d_in[0];
    const float* w1  = (const float*)d_in[1];
    const float* w2  = (const float*)d_in[2];
    const float* w3  = (const float*)d_in[3];
    const int*   ia1 = (const int*)d_in[4];
    const int*   ib1 = (const int*)d_in[5];
    const int*   ia2 = (const int*)d_in[6];
    const int*   ib2 = (const int*)d_in[7];
    const int*   ia3 = (const int*)d_in[8];
    const int*   ib3 = (const int*)d_in[9];
    float* out = (float*)d_out;

    // workspace: xT (0.5MB) | leaf (2MB) | pc (7MB)  ~= 9.5 MB
    char* ws = (char*)d_ws;
    ushort_t* xT = (ushort_t*)ws;
    int*    leaf = (int*)(ws + (size_t)IN_DIM * BATCH * 2);
    float4*   pc = (float4*)(leaf + (size_t)WIDTH * 8);

    hipMemsetAsync(d_out, 0, (size_t)out_size * sizeof(float), stream);

    transpose_kernel<<<64, 256, 0, stream>>>(x, xT);
    prep_kernel<<<WIDTH / 256, 256, 0, stream>>>(w1, w2, w3,
                                                 ia1, ib1, ia2, ib2, ia3, ib3,
                                                 leaf, pc);
    fused_kernel<<<NBLK, 512, 0, stream>>>(xT, leaf, pc, out);
}

// Round 5
// 221.030 us; speedup vs baseline: 1.8765x; 1.8765x over previous
//
#include <hip/hip_runtime.h>
#include <stdint.h>

// DiffLogic: 3-layer differentiable logic network.
// Round 11: R10's pipeline was right, its implementation spilled: passing
// the G8 aggregate by reference defeated SROA -> cur/nxt went address-taken
// into scratch (VGPR=64, WRITE_SIZE=632MB, 31ms cold dispatch). Same idea,
// spill-proof expression:
//  - 16 NAMED uint2 registers (sets A/B), macro load/compute, full unroll,
//    zero aggregates, zero references -> nothing can be address-taken.
//  - __launch_bounds__(512,2): VGPR cap 256, no incentive to spill ~110.
//  - packed bf16 upconvert (u<<16 / u&0xffff0000): 2 ops per 2 elems.
//  - softmax split back into a coalesced coef_kernel; prep just gathers.

#define BATCH   256
#define IN_DIM  1024
#define WIDTH   64000
#define NGROUP  10
#define GSIZE   6400      // WIDTH / NGROUP
#define TAU     30.0f
#define NWAVE   8         // waves per block (512 threads)
#define GPW     8         // gates per wave
#define GPB     (NWAVE*GPW)   // 64 gates/block
#define NBLK    (WIDTH/GPB)   // 1000

typedef unsigned short ushort_t;

static __device__ __forceinline__ ushort_t f2bf(float f) {   // RNE
    uint32_t u = __float_as_uint(f);
    return (ushort_t)((u + 0x7fffu + ((u >> 16) & 1u)) >> 16);
}
static __device__ __forceinline__ float bfl(uint32_t u) {    // low bf16 -> f32
    return __uint_as_float(u << 16);
}
static __device__ __forceinline__ float bfh(uint32_t u) {    // high bf16 -> f32
    return __uint_as_float(u & 0xffff0000u);
}
// h = c0 + c1*a + c2*b + c3*(a*b) = b*(c3*a+c2) + (c1*a+c0)  -- 3 FMA/elem
static __device__ __forceinline__ float gate1(float4 c, float a, float b) {
    return fmaf(b, fmaf(c.w, a, c.z), fmaf(c.y, a, c.x));
}
static __device__ __forceinline__ float4 gate4(float4 c, float4 a, float4 b) {
    float4 r;
    r.x = gate1(c, a.x, b.x);
    r.y = gate1(c, a.y, b.y);
    r.z = gate1(c, a.z, b.z);
    r.w = gate1(c, a.w, b.w);
    return r;
}
// packed inputs: a,b are uint2 holding 4 bf16 (batch elems) each
static __device__ __forceinline__ float4 gate4p(float4 c, uint2 a, uint2 b) {
    float4 r;
    r.x = gate1(c, bfl(a.x), bfl(b.x));
    r.y = gate1(c, bfh(a.x), bfh(b.x));
    r.z = gate1(c, bfl(a.y), bfl(b.y));
    r.w = gate1(c, bfh(a.y), bfh(b.y));
    return r;
}

// ---------------------------------------------------------------- transpose
// x:(256,1024) f32 row-major -> xT:(1024,256) bf16
__global__ __launch_bounds__(256) void transpose_kernel(
    const float* __restrict__ x, ushort_t* __restrict__ xT)
{
    __shared__ float tile[64][65];
    const int c0 = (blockIdx.x & 15) * 64;
    const int b0 = (blockIdx.x >> 4) * 64;
    const int lt = threadIdx.x & 63;
    const int wt = threadIdx.x >> 6;
    for (int r = wt; r < 64; r += 4)
        tile[r][lt] = x[(b0 + r) * IN_DIM + c0 + lt];
    __syncthreads();
    for (int r = wt; r < 64; r += 4)
        xT[(c0 + r) * BATCH + b0 + lt] = f2bf(tile[lt][r]);
}

// ---------------------------------------------------------------- coefficients
__global__ __launch_bounds__(256) void coef_kernel(
    const float* __restrict__ w1, const float* __restrict__ w2,
    const float* __restrict__ w3,
    float4* __restrict__ c1o, float4* __restrict__ c2o, float4* __restrict__ c3o)
{
    const int id = blockIdx.x * 256 + threadIdx.x;
    const int layer = id / WIDTH;
    const int j = id - layer * WIDTH;
    const float* w = (layer == 0) ? w1 : (layer == 1) ? w2 : w3;
    float4* cc     = (layer == 0) ? c1o : (layer == 1) ? c2o : c3o;

    const float4* w4 = (const float4*)(w + (size_t)j * 16);
    float4 q0 = w4[0], q1 = w4[1], q2 = w4[2], q3 = w4[3];
    float p[16] = {q0.x,q0.y,q0.z,q0.w, q1.x,q1.y,q1.z,q1.w,
                   q2.x,q2.y,q2.z,q2.w, q3.x,q3.y,q3.z,q3.w};
    float m = p[0];
    #pragma unroll
    for (int i = 1; i < 16; ++i) m = fmaxf(m, p[i]);
    float s = 0.f;
    #pragma unroll
    for (int i = 0; i < 16; ++i) { p[i] = __expf(p[i] - m); s += p[i]; }
    const float inv = 1.0f / s;
    float c0 = (p[8]+p[9]+p[10]+p[11]+p[12]+p[13]+p[14]+p[15]) * inv;
    float c1 = (p[2]+p[3]+p[6]+p[7] - p[8]-p[9]-p[12]-p[13]) * inv;
    float c2 = (p[4]+p[5]+p[6]+p[7] - p[8]-p[9]-p[10]-p[11]) * inv;
    float c3 = (p[1]-p[2]-p[4]-2.f*p[6]-p[7]+p[8]+2.f*p[9]+p[11]+p[13]-p[14]) * inv;
    cc[j] = make_float4(c0, c1, c2, c3);
}

// ---------------------------------------------------------------- tree prep
// One thread per final gate j: flatten its depth-3 tree into 8 leaf x-indices
// + 7 precomputed coefficient float4s (contiguous per gate).
__global__ __launch_bounds__(256) void prep_kernel(
    const int* __restrict__ ia1, const int* __restrict__ ib1,
    const int* __restrict__ ia2, const int* __restrict__ ib2,
    const int* __restrict__ ia3, const int* __restrict__ ib3,
    const float4* __restrict__ c1, const float4* __restrict__ c2,
    const float4* __restrict__ c3,
    int* __restrict__ leaf,        // [WIDTH][8]
    float4* __restrict__ pc)       // [WIDTH][7]
{
    const int j = blockIdx.x * 256 + threadIdx.x;
    if (j >= WIDTH) return;

    const int pa = ia3[j], pb = ib3[j];
    const int qaa = ia2[pa], qab = ib2[pa];
    const int qba = ia2[pb], qbb = ib2[pb];

    int* L = leaf + (size_t)j * 8;
    L[0] = ia1[qaa]; L[1] = ib1[qaa];
    L[2] = ia1[qab]; L[3] = ib1[qab];
    L[4] = ia1[qba]; L[5] = ib1[qba];
    L[6] = ia1[qbb]; L[7] = ib1[qbb];

    float4* P = pc + (size_t)j * 7;
    P[0] = c1[qaa]; P[1] = c1[qab]; P[2] = c1[qba]; P[3] = c1[qbb];
    P[4] = c2[pa];  P[5] = c2[pb];
    P[6] = c3[j];
}

// ---------------------------------------------------------------- fused net
// Depth-2 software pipeline over named registers. LOADG pulls one gate's 8
// leaf columns (uint2 = 4 packed bf16 batch elems / lane); COMPG evaluates
// the 7-gate tree and accumulates. A/B sets alternate; everything is
// compile-time indexed so nothing can reach scratch.
#define LOADG(q0,q1,q2,q3,q4,q5,q6,q7, g) do {                                 \
    const int _g8 = (g) * 8;                                                   \
    const int _c0 = __builtin_amdgcn_readfirstlane(sleaf[_g8 + 0]);            \
    const int _c1 = __builtin_amdgcn_readfirstlane(sleaf[_g8 + 1]);            \
    const int _c2 = __builtin_amdgcn_readfirstlane(sleaf[_g8 + 2]);            \
    const int _c3 = __builtin_amdgcn_readfirstlane(sleaf[_g8 + 3]);            \
    const int _c4 = __builtin_amdgcn_readfirstlane(sleaf[_g8 + 4]);            \
    const int _c5 = __builtin_amdgcn_readfirstlane(sleaf[_g8 + 5]);            \
    const int _c6 = __builtin_amdgcn_readfirstlane(sleaf[_g8 + 6]);            \
    const int _c7 = __builtin_amdgcn_readfirstlane(sleaf[_g8 + 7]);            \
    q0 = ((const uint2*)(xT + (size_t)_c0 * BATCH))[lane];                     \
    q1 = ((const uint2*)(xT + (size_t)_c1 * BATCH))[lane];                     \
    q2 = ((const uint2*)(xT + (size_t)_c2 * BATCH))[lane];                     \
    q3 = ((const uint2*)(xT + (size_t)_c3 * BATCH))[lane];                     \
    q4 = ((const uint2*)(xT + (size_t)_c4 * BATCH))[lane];                     \
    q5 = ((const uint2*)(xT + (size_t)_c5 * BATCH))[lane];                     \
    q6 = ((const uint2*)(xT + (size_t)_c6 * BATCH))[lane];                     \
    q7 = ((const uint2*)(xT + (size_t)_c7 * BATCH))[lane];                     \
} while (0)

#define COMPG(q0,q1,q2,q3,q4,q5,q6,q7, g) do {                                 \
    const int _g7 = (g) * 7;                                                   \
    const float4 _haa = gate4p(spc[_g7 + 0], q0, q1);                          \
    const float4 _hab = gate4p(spc[_g7 + 1], q2, q3);                          \
    const float4 _hba = gate4p(spc[_g7 + 2], q4, q5);                          \
    const float4 _hbb = gate4p(spc[_g7 + 3], q6, q7);                          \
    const float4 _h2a = gate4(spc[_g7 + 4], _haa, _hab);                       \
    const float4 _h2b = gate4(spc[_g7 + 5], _hba, _hbb);                       \
    const float4 _h3  = gate4(spc[_g7 + 6], _h2a, _h2b);                       \
    acc.x += _h3.x; acc.y += _h3.y; acc.z += _h3.z; acc.w += _h3.w;            \
} while (0)

__global__ __launch_bounds__(512, 2) void fused_kernel(
    const ushort_t* __restrict__ xT,
    const int*      __restrict__ leaf,
    const float4*   __restrict__ pc,
    float*          __restrict__ red_out)
{
    __shared__ int    sleaf[GPB * 8];        // 2 KB
    __shared__ float4 spc[GPB * 7];          // 7 KB
    __shared__ float4 sred[NWAVE][64];       // 8 KB

    const int tid = threadIdx.x;

    // ---- coalesced metadata stage (block's spans are contiguous)
    sleaf[tid] = leaf[(size_t)blockIdx.x * (GPB * 8) + tid];      // 512 x 4B
    if (tid < GPB * 7)
        spc[tid] = pc[(size_t)blockIdx.x * (GPB * 7) + tid];      // 448 x 16B
    __syncthreads();

    const int lane = tid & 63;
    const int wave = tid >> 6;
    const int g0 = wave * GPW;

    uint2 A0, A1, A2, A3, A4, A5, A6, A7;
    uint2 B0, B1, B2, B3, B4, B5, B6, B7;

    LOADG(A0,A1,A2,A3,A4,A5,A6,A7, g0 + 0);
    LOADG(B0,B1,B2,B3,B4,B5,B6,B7, g0 + 1);

    float4 acc = make_float4(0.f, 0.f, 0.f, 0.f);

    COMPG(A0,A1,A2,A3,A4,A5,A6,A7, g0 + 0);
    LOADG(A0,A1,A2,A3,A4,A5,A6,A7, g0 + 2);
    COMPG(B0,B1,B2,B3,B4,B5,B6,B7, g0 + 1);
    LOADG(B0,B1,B2,B3,B4,B5,B6,B7, g0 + 3);
    COMPG(A0,A1,A2,A3,A4,A5,A6,A7, g0 + 2);
    LOADG(A0,A1,A2,A3,A4,A5,A6,A7, g0 + 4);
    COMPG(B0,B1,B2,B3,B4,B5,B6,B7, g0 + 3);
    LOADG(B0,B1,B2,B3,B4,B5,B6,B7, g0 + 5);
    COMPG(A0,A1,A2,A3,A4,A5,A6,A7, g0 + 4);
    LOADG(A0,A1,A2,A3,A4,A5,A6,A7, g0 + 6);
    COMPG(B0,B1,B2,B3,B4,B5,B6,B7, g0 + 5);
    LOADG(B0,B1,B2,B3,B4,B5,B6,B7, g0 + 7);
    COMPG(A0,A1,A2,A3,A4,A5,A6,A7, g0 + 6);
    COMPG(B0,B1,B2,B3,B4,B5,B6,B7, g0 + 7);

    // ---- block reduction + grouped atomic add
    sred[wave][lane] = acc;
    __syncthreads();
    if (wave == 0) {
        float4 t = sred[0][lane];
        #pragma unroll
        for (int w = 1; w < NWAVE; ++w) {
            float4 q = sred[w][lane];
            t.x += q.x; t.y += q.y; t.z += q.z; t.w += q.w;
        }
        const float sc = 1.0f / TAU;
        const int grp = (blockIdx.x * GPB) / GSIZE;
        const int b0 = lane * 4;
        atomicAdd(&red_out[(b0 + 0) * NGROUP + grp], t.x * sc);
        atomicAdd(&red_out[(b0 + 1) * NGROUP + grp], t.y * sc);
        atomicAdd(&red_out[(b0 + 2) * NGROUP + grp], t.z * sc);
        atomicAdd(&red_out[(b0 + 3) * NGROUP + grp], t.w * sc);
    }
}

// ---------------------------------------------------------------- launch
extern "C" void kernel_launch(void* const* d_in, const int* in_sizes, int n_in,
                              void* d_out, int out_size, void* d_ws, size_t ws_size,
                              hipStream_t stream)
{
    const float* x   = (const float*)d_in[0];
    const float* w1  = (const float*)d_in[1];
    const float* w2  = (const float*)d_in[2];
    const float* w3  = (const float*)d_in[3];
    const int*   ia1 = (const int*)d_in[4];
    const int*   ib1 = (const int*)d_in[5];
    const int*   ia2 = (const int*)d_in[6];
    const int*   ib2 = (const int*)d_in[7];
    const int*   ia3 = (const int*)d_in[8];
    const int*   ib3 = (const int*)d_in[9];
    float* out = (float*)d_out;

    // workspace: xT (0.5MB) | leaf (2MB) | pc (7MB) | c1,c2,c3 (3MB) ~= 12.5MB
    char* ws = (char*)d_ws;
    ushort_t* xT = (ushort_t*)ws;
    int*    leaf = (int*)(ws + (size_t)IN_DIM * BATCH * 2);
    float4*   pc = (float4*)(leaf + (size_t)WIDTH * 8);
    float4*   c1 = pc + (size_t)WIDTH * 7;
    float4*   c2 = c1 + WIDTH;
    float4*   c3 = c2 + WIDTH;

    hipMemsetAsync(d_out, 0, (size_t)out_size * sizeof(float), stream);

    transpose_kernel<<<64, 256, 0, stream>>>(x, xT);
    coef_kernel<<<(3 * WIDTH) / 256, 256, 0, stream>>>(w1, w2, w3, c1, c2, c3);
    prep_kernel<<<WIDTH / 256, 256, 0, stream>>>(ia1, ib1, ia2, ib2, ia3, ib3,
                                                 c1, c2, c3, leaf, pc);
    fused_kernel<<<NBLK, 512, 0, stream>>>(xT, leaf, pc, out);
}

// Round 6
// 152.124 us; speedup vs baseline: 2.7266x; 1.4530x over previous
//
#include <hip/hip_runtime.h>
#include <stdint.h>

// DiffLogic: 3-layer differentiable logic network.
// Round 12: stop fighting the register allocator. R10/R11 both spilled the
// gather-pipeline state (WRITE_SIZE 632/230 MB of scratch on a 10MB-traffic
// kernel). New fused structure has ZERO live gather state:
//  - batch sliced 4x -> x-slice (1024 cols x 64 batch, bf16) = 128KB,
//    LDS-resident. Every leaf access is a ~64cy conflict-free ds_read_u16
//    (lane = batch elem; 2 lanes/dword -> broadcast-merge, free).
//  - gate metadata barrier-staged 128 gates at a time (18KB, proven R1/R3).
//  - per-gate data consumed immediately; live state = 2 scalar accs.
//  - block = 512 gates x 1 slice; grid = 125 chunks x 4 slices = 500.
//  - group straddle (6400 % 512 != 0) handled by dual acc + uniform branch.

#define BATCH   256
#define IN_DIM  1024
#define WIDTH   64000
#define NGROUP  10
#define GSIZE   6400      // WIDTH / NGROUP
#define TAU     30.0f
#define NWAVE   8         // waves per block (512 threads)
#define SLICES  4
#define SB      64        // batch elems per slice
#define GPB2    512       // gates per block
#define NCHUNK  (WIDTH/GPB2)   // 125
#define MCH     128       // gates per metadata stage
#define NBLK    (NCHUNK*SLICES) // 500

typedef unsigned short ushort_t;

static __device__ __forceinline__ ushort_t f2bf(float f) {   // RNE
    uint32_t u = __float_as_uint(f);
    return (ushort_t)((u + 0x7fffu + ((u >> 16) & 1u)) >> 16);
}
static __device__ __forceinline__ float bfu(ushort_t s) {    // bf16 -> f32
    return __uint_as_float((uint32_t)s << 16);
}
// h = c0 + c1*a + c2*b + c3*(a*b) = b*(c3*a+c2) + (c1*a+c0)  -- 3 FMA
static __device__ __forceinline__ float gate1(float4 c, float a, float b) {
    return fmaf(b, fmaf(c.w, a, c.z), fmaf(c.y, a, c.x));
}

// ---------------------------------------------------------------- transpose
// x:(256,1024) f32 row-major -> xT:(1024,256) bf16
__global__ __launch_bounds__(256) void transpose_kernel(
    const float* __restrict__ x, ushort_t* __restrict__ xT)
{
    __shared__ float tile[64][65];
    const int c0 = (blockIdx.x & 15) * 64;
    const int b0 = (blockIdx.x >> 4) * 64;
    const int lt = threadIdx.x & 63;
    const int wt = threadIdx.x >> 6;
    for (int r = wt; r < 64; r += 4)
        tile[r][lt] = x[(b0 + r) * IN_DIM + c0 + lt];
    __syncthreads();
    for (int r = wt; r < 64; r += 4)
        xT[(c0 + r) * BATCH + b0 + lt] = f2bf(tile[lt][r]);
}

// ---------------------------------------------------------------- coefficients
__global__ __launch_bounds__(256) void coef_kernel(
    const float* __restrict__ w1, const float* __restrict__ w2,
    const float* __restrict__ w3,
    float4* __restrict__ c1o, float4* __restrict__ c2o, float4* __restrict__ c3o)
{
    const int id = blockIdx.x * 256 + threadIdx.x;
    const int layer = id / WIDTH;
    const int j = id - layer * WIDTH;
    const float* w = (layer == 0) ? w1 : (layer == 1) ? w2 : w3;
    float4* cc     = (layer == 0) ? c1o : (layer == 1) ? c2o : c3o;

    const float4* w4 = (const float4*)(w + (size_t)j * 16);
    float4 q0 = w4[0], q1 = w4[1], q2 = w4[2], q3 = w4[3];
    float p[16] = {q0.x,q0.y,q0.z,q0.w, q1.x,q1.y,q1.z,q1.w,
                   q2.x,q2.y,q2.z,q2.w, q3.x,q3.y,q3.z,q3.w};
    float m = p[0];
    #pragma unroll
    for (int i = 1; i < 16; ++i) m = fmaxf(m, p[i]);
    float s = 0.f;
    #pragma unroll
    for (int i = 0; i < 16; ++i) { p[i] = __expf(p[i] - m); s += p[i]; }
    const float inv = 1.0f / s;
    float c0 = (p[8]+p[9]+p[10]+p[11]+p[12]+p[13]+p[14]+p[15]) * inv;
    float c1 = (p[2]+p[3]+p[6]+p[7] - p[8]-p[9]-p[12]-p[13]) * inv;
    float c2 = (p[4]+p[5]+p[6]+p[7] - p[8]-p[9]-p[10]-p[11]) * inv;
    float c3 = (p[1]-p[2]-p[4]-2.f*p[6]-p[7]+p[8]+2.f*p[9]+p[11]+p[13]-p[14]) * inv;
    cc[j] = make_float4(c0, c1, c2, c3);
}

// ---------------------------------------------------------------- tree prep
__global__ __launch_bounds__(256) void prep_kernel(
    const int* __restrict__ ia1, const int* __restrict__ ib1,
    const int* __restrict__ ia2, const int* __restrict__ ib2,
    const int* __restrict__ ia3, const int* __restrict__ ib3,
    const float4* __restrict__ c1, const float4* __restrict__ c2,
    const float4* __restrict__ c3,
    int* __restrict__ leaf,        // [WIDTH][8]
    float4* __restrict__ pc)       // [WIDTH][7]
{
    const int j = blockIdx.x * 256 + threadIdx.x;
    if (j >= WIDTH) return;

    const int pa = ia3[j], pb = ib3[j];
    const int qaa = ia2[pa], qab = ib2[pa];
    const int qba = ia2[pb], qbb = ib2[pb];

    int* L = leaf + (size_t)j * 8;
    L[0] = ia1[qaa]; L[1] = ib1[qaa];
    L[2] = ia1[qab]; L[3] = ib1[qab];
    L[4] = ia1[qba]; L[5] = ib1[qba];
    L[6] = ia1[qbb]; L[7] = ib1[qbb];

    float4* P = pc + (size_t)j * 7;
    P[0] = c1[qaa]; P[1] = c1[qab]; P[2] = c1[qba]; P[3] = c1[qbb];
    P[4] = c2[pa];  P[5] = c2[pb];
    P[6] = c3[j];
}

// ---------------------------------------------------------------- fused net
__global__ __launch_bounds__(512) void fused_kernel(
    const ushort_t* __restrict__ xT,
    const int*      __restrict__ leaf,
    const float4*   __restrict__ pc,
    float*          __restrict__ red_out)
{
    __shared__ ushort_t xs[IN_DIM * SB];     // 128 KB  x-slice
    __shared__ int      sml[MCH * 8];        // 4 KB    leaf idx chunk
    __shared__ float4   smc[MCH * 7];        // 14 KB   coef chunk
    __shared__ float2   sred[NWAVE][64];     // 4 KB    reduction

    const int tid   = threadIdx.x;
    const int lane  = tid & 63;
    const int wave  = tid >> 6;
    const int chunk = blockIdx.x >> 2;       // 0..124
    const int slice = blockIdx.x & 3;        // 0..3

    // ---- stage x slice (1024 cols x 64 batch, bf16): 8B per thread-pass
    {
        const int sub = tid & 15;            // 16 x 8B = one 128B row
        const int r0  = tid >> 4;            // 32 rows per pass
        for (int p = 0; p < 32; ++p) {
            const int row = p * 32 + r0;
            const uint2 v = *(const uint2*)(xT + (size_t)row * BATCH + slice * SB + sub * 4);
            *(uint2*)(xs + row * SB + sub * 4) = v;
        }
    }

    const int gate0 = chunk * GPB2;                 // block's first gate
    const int grp0  = gate0 / GSIZE;
    const int split = (grp0 + 1) * GSIZE - gate0;   // local gates in grp0

    float acc0 = 0.f, acc1 = 0.f;

    for (int ci = 0; ci < GPB2 / MCH; ++ci) {       // 4 metadata chunks
        __syncthreads();                            // prev compute / x staged
        const size_t mb = (size_t)(gate0 + ci * MCH);
        ((int2*)sml)[tid] = ((const int2*)(leaf + mb * 8))[tid];   // 1024 ints
        smc[tid] = pc[mb * 7 + tid];                               // 512
        if (tid < MCH * 7 - 512)
            smc[512 + tid] = pc[mb * 7 + 512 + tid];               // +384
        __syncthreads();

        const int gw = wave * (MCH / NWAVE);        // 16 gates / wave
        #pragma unroll 2
        for (int i = 0; i < MCH / NWAVE; ++i) {
            const int g = gw + i;
            const int c0 = __builtin_amdgcn_readfirstlane(sml[g*8 + 0]);
            const int c1 = __builtin_amdgcn_readfirstlane(sml[g*8 + 1]);
            const int c2 = __builtin_amdgcn_readfirstlane(sml[g*8 + 2]);
            const int c3 = __builtin_amdgcn_readfirstlane(sml[g*8 + 3]);
            const int c4 = __builtin_amdgcn_readfirstlane(sml[g*8 + 4]);
            const int c5 = __builtin_amdgcn_readfirstlane(sml[g*8 + 5]);
            const int c6 = __builtin_amdgcn_readfirstlane(sml[g*8 + 6]);
            const int c7 = __builtin_amdgcn_readfirstlane(sml[g*8 + 7]);

            const float v0 = bfu(xs[c0 * SB + lane]);
            const float v1 = bfu(xs[c1 * SB + lane]);
            const float v2 = bfu(xs[c2 * SB + lane]);
            const float v3 = bfu(xs[c3 * SB + lane]);
            const float v4 = bfu(xs[c4 * SB + lane]);
            const float v5 = bfu(xs[c5 * SB + lane]);
            const float v6 = bfu(xs[c6 * SB + lane]);
            const float v7 = bfu(xs[c7 * SB + lane]);

            const float haa = gate1(smc[g*7 + 0], v0, v1);
            const float hab = gate1(smc[g*7 + 1], v2, v3);
            const float hba = gate1(smc[g*7 + 2], v4, v5);
            const float hbb = gate1(smc[g*7 + 3], v6, v7);
            const float h2a = gate1(smc[g*7 + 4], haa, hab);
            const float h2b = gate1(smc[g*7 + 5], hba, hbb);
            const float h3  = gate1(smc[g*7 + 6], h2a, h2b);

            const int gl = ci * MCH + g;            // wave-uniform
            if (gl < split) acc0 += h3; else acc1 += h3;
        }
    }

    // ---- block reduction + grouped atomic add
    sred[wave][lane] = make_float2(acc0, acc1);
    __syncthreads();
    if (wave == 0) {
        float t0 = 0.f, t1 = 0.f;
        #pragma unroll
        for (int w = 0; w < NWAVE; ++w) {
            const float2 q = sred[w][lane];
            t0 += q.x; t1 += q.y;
        }
        const float sc = 1.0f / TAU;
        const int b = slice * SB + lane;            // batch elem
        atomicAdd(&red_out[b * NGROUP + grp0], t0 * sc);
        if (split < GPB2)
            atomicAdd(&red_out[b * NGROUP + grp0 + 1], t1 * sc);
    }
}

// ---------------------------------------------------------------- launch
extern "C" void kernel_launch(void* const* d_in, const int* in_sizes, int n_in,
                              void* d_out, int out_size, void* d_ws, size_t ws_size,
                              hipStream_t stream)
{
    const float* x   = (const float*)d_in[0];
    const float* w1  = (const float*)d_in[1];
    const float* w2  = (const float*)d_in[2];
    const float* w3  = (const float*)d_in[3];
    const int*   ia1 = (const int*)d_in[4];
    const int*   ib1 = (const int*)d_in[5];
    const int*   ia2 = (const int*)d_in[6];
    const int*   ib2 = (const int*)d_in[7];
    const int*   ia3 = (const int*)d_in[8];
    const int*   ib3 = (const int*)d_in[9];
    float* out = (float*)d_out;

    // workspace: xT (0.5MB) | leaf (2MB) | pc (7MB) | c1,c2,c3 (3MB) ~= 12.5MB
    char* ws = (char*)d_ws;
    ushort_t* xT = (ushort_t*)ws;
    int*    leaf = (int*)(ws + (size_t)IN_DIM * BATCH * 2);
    float4*   pc = (float4*)(leaf + (size_t)WIDTH * 8);
    float4*   c1 = pc + (size_t)WIDTH * 7;
    float4*   c2 = c1 + WIDTH;
    float4*   c3 = c2 + WIDTH;

    hipMemsetAsync(d_out, 0, (size_t)out_size * sizeof(float), stream);

    transpose_kernel<<<64, 256, 0, stream>>>(x, xT);
    coef_kernel<<<(3 * WIDTH) / 256, 256, 0, stream>>>(w1, w2, w3, c1, c2, c3);
    prep_kernel<<<WIDTH / 256, 256, 0, stream>>>(ia1, ib1, ia2, ib2, ia3, ib3,
                                                 c1, c2, c3, leaf, pc);
    fused_kernel<<<NBLK, 512, 0, stream>>>(xT, leaf, pc, out);
}

// Round 7
// 142.967 us; speedup vs baseline: 2.9012x; 1.0640x over previous
//
#include <hip/hip_runtime.h>
#include <stdint.h>

// DiffLogic: 3-layer differentiable logic network.
// Round 13: R12 killed the spill (WRITE 1MB, VGPR 88) but runs 1 block/CU
// (150KB LDS) x 512 threads = 2 waves/SIMD -> VALUBusy 42%, latency-bound.
// Same structure, 1024-thread block = 16 waves on the SAME LDS budget ->
// 4 waves/SIMD, 2x latency hiding. __launch_bounds__(1024,4) pins the
// VGPR cap at 128 (R8's spill came from the default bound targeting 64).
// Idx reads: two uniform int4 ds_read_b128 per gate instead of 8x b32.

#define BATCH   256
#define IN_DIM  1024
#define WIDTH   64000
#define NGROUP  10
#define GSIZE   6400      // WIDTH / NGROUP
#define TAU     30.0f
#define NWAVE   16        // waves per block (1024 threads)
#define SLICES  4
#define SB      64        // batch elems per slice
#define GPB2    512       // gates per block
#define NCHUNK  (WIDTH/GPB2)   // 125
#define MCH     128       // gates per metadata stage
#define GPWC    (MCH/NWAVE)    // 8 gates per wave per chunk
#define NBLK    (NCHUNK*SLICES) // 500

typedef unsigned short ushort_t;

static __device__ __forceinline__ ushort_t f2bf(float f) {   // RNE
    uint32_t u = __float_as_uint(f);
    return (ushort_t)((u + 0x7fffu + ((u >> 16) & 1u)) >> 16);
}
static __device__ __forceinline__ float bfu(ushort_t s) {    // bf16 -> f32
    return __uint_as_float((uint32_t)s << 16);
}
// h = c0 + c1*a + c2*b + c3*(a*b) = b*(c3*a+c2) + (c1*a+c0)  -- 3 FMA
static __device__ __forceinline__ float gate1(float4 c, float a, float b) {
    return fmaf(b, fmaf(c.w, a, c.z), fmaf(c.y, a, c.x));
}

// ---------------------------------------------------------------- transpose
// x:(256,1024) f32 row-major -> xT:(1024,256) bf16
__global__ __launch_bounds__(256) void transpose_kernel(
    const float* __restrict__ x, ushort_t* __restrict__ xT)
{
    __shared__ float tile[64][65];
    const int c0 = (blockIdx.x & 15) * 64;
    const int b0 = (blockIdx.x >> 4) * 64;
    const int lt = threadIdx.x & 63;
    const int wt = threadIdx.x >> 6;
    for (int r = wt; r < 64; r += 4)
        tile[r][lt] = x[(b0 + r) * IN_DIM + c0 + lt];
    __syncthreads();
    for (int r = wt; r < 64; r += 4)
        xT[(c0 + r) * BATCH + b0 + lt] = f2bf(tile[lt][r]);
}

// ---------------------------------------------------------------- coefficients
__global__ __launch_bounds__(256) void coef_kernel(
    const float* __restrict__ w1, const float* __restrict__ w2,
    const float* __restrict__ w3,
    float4* __restrict__ c1o, float4* __restrict__ c2o, float4* __restrict__ c3o)
{
    const int id = blockIdx.x * 256 + threadIdx.x;
    const int layer = id / WIDTH;
    const int j = id - layer * WIDTH;
    const float* w = (layer == 0) ? w1 : (layer == 1) ? w2 : w3;
    float4* cc     = (layer == 0) ? c1o : (layer == 1) ? c2o : c3o;

    const float4* w4 = (const float4*)(w + (size_t)j * 16);
    float4 q0 = w4[0], q1 = w4[1], q2 = w4[2], q3 = w4[3];
    float p[16] = {q0.x,q0.y,q0.z,q0.w, q1.x,q1.y,q1.z,q1.w,
                   q2.x,q2.y,q2.z,q2.w, q3.x,q3.y,q3.z,q3.w};
    float m = p[0];
    #pragma unroll
    for (int i = 1; i < 16; ++i) m = fmaxf(m, p[i]);
    float s = 0.f;
    #pragma unroll
    for (int i = 0; i < 16; ++i) { p[i] = __expf(p[i] - m); s += p[i]; }
    const float inv = 1.0f / s;
    float c0 = (p[8]+p[9]+p[10]+p[11]+p[12]+p[13]+p[14]+p[15]) * inv;
    float c1 = (p[2]+p[3]+p[6]+p[7] - p[8]-p[9]-p[12]-p[13]) * inv;
    float c2 = (p[4]+p[5]+p[6]+p[7] - p[8]-p[9]-p[10]-p[11]) * inv;
    float c3 = (p[1]-p[2]-p[4]-2.f*p[6]-p[7]+p[8]+2.f*p[9]+p[11]+p[13]-p[14]) * inv;
    cc[j] = make_float4(c0, c1, c2, c3);
}

// ---------------------------------------------------------------- tree prep
__global__ __launch_bounds__(256) void prep_kernel(
    const int* __restrict__ ia1, const int* __restrict__ ib1,
    const int* __restrict__ ia2, const int* __restrict__ ib2,
    const int* __restrict__ ia3, const int* __restrict__ ib3,
    const float4* __restrict__ c1, const float4* __restrict__ c2,
    const float4* __restrict__ c3,
    int* __restrict__ leaf,        // [WIDTH][8]
    float4* __restrict__ pc)       // [WIDTH][7]
{
    const int j = blockIdx.x * 256 + threadIdx.x;
    if (j >= WIDTH) return;

    const int pa = ia3[j], pb = ib3[j];
    const int qaa = ia2[pa], qab = ib2[pa];
    const int qba = ia2[pb], qbb = ib2[pb];

    int* L = leaf + (size_t)j * 8;
    L[0] = ia1[qaa]; L[1] = ib1[qaa];
    L[2] = ia1[qab]; L[3] = ib1[qab];
    L[4] = ia1[qba]; L[5] = ib1[qba];
    L[6] = ia1[qbb]; L[7] = ib1[qbb];

    float4* P = pc + (size_t)j * 7;
    P[0] = c1[qaa]; P[1] = c1[qab]; P[2] = c1[qba]; P[3] = c1[qbb];
    P[4] = c2[pa];  P[5] = c2[pb];
    P[6] = c3[j];
}

// ---------------------------------------------------------------- fused net
__global__ __launch_bounds__(1024, 4) void fused_kernel(
    const ushort_t* __restrict__ xT,
    const int*      __restrict__ leaf,
    const float4*   __restrict__ pc,
    float*          __restrict__ red_out)
{
    __shared__ ushort_t xs[IN_DIM * SB];     // 128 KB  x-slice
    __shared__ int      sml[MCH * 8];        // 4 KB    leaf idx chunk
    __shared__ float4   smc[MCH * 7];        // 14 KB   coef chunk
    __shared__ float2   sred[NWAVE][64];     // 8 KB    reduction

    const int tid   = threadIdx.x;
    const int lane  = tid & 63;
    const int wave  = tid >> 6;
    const int chunk = blockIdx.x >> 2;       // 0..124
    const int slice = blockIdx.x & 3;        // 0..3

    // ---- stage x slice (1024 cols x 64 batch, bf16): 128 B per thread
    {
        const int sub = tid & 15;            // 16 x 8B = one 128B row
        const int r0  = tid >> 4;            // 64 rows per pass
        for (int p = 0; p < 16; ++p) {
            const int row = p * 64 + r0;
            const uint2 v = *(const uint2*)(xT + (size_t)row * BATCH + slice * SB + sub * 4);
            *(uint2*)(xs + row * SB + sub * 4) = v;
        }
    }

    const int gate0 = chunk * GPB2;                 // block's first gate
    const int grp0  = gate0 / GSIZE;
    const int split = (grp0 + 1) * GSIZE - gate0;   // local gates in grp0

    float acc0 = 0.f, acc1 = 0.f;

    for (int ci = 0; ci < GPB2 / MCH; ++ci) {       // 4 metadata chunks
        __syncthreads();                            // prev compute / x staged
        const size_t mb = (size_t)(gate0 + ci * MCH);
        sml[tid] = leaf[mb * 8 + tid];              // 1024 ints, one each
        if (tid < MCH * 7)
            smc[tid] = pc[mb * 7 + tid];            // 896 float4
        __syncthreads();

        const int gw = wave * GPWC;                 // 8 gates / wave
        #pragma unroll 2
        for (int i = 0; i < GPWC; ++i) {
            const int g = gw + i;
            // two uniform ds_read_b128 for the 8 leaf indices
            const int4 iA = *((const int4*)(sml + g * 8));
            const int4 iB = *((const int4*)(sml + g * 8 + 4));
            const int c0 = __builtin_amdgcn_readfirstlane(iA.x);
            const int c1 = __builtin_amdgcn_readfirstlane(iA.y);
            const int c2 = __builtin_amdgcn_readfirstlane(iA.z);
            const int c3 = __builtin_amdgcn_readfirstlane(iA.w);
            const int c4 = __builtin_amdgcn_readfirstlane(iB.x);
            const int c5 = __builtin_amdgcn_readfirstlane(iB.y);
            const int c6 = __builtin_amdgcn_readfirstlane(iB.z);
            const int c7 = __builtin_amdgcn_readfirstlane(iB.w);

            const float v0 = bfu(xs[c0 * SB + lane]);
            const float v1 = bfu(xs[c1 * SB + lane]);
            const float v2 = bfu(xs[c2 * SB + lane]);
            const float v3 = bfu(xs[c3 * SB + lane]);
            const float v4 = bfu(xs[c4 * SB + lane]);
            const float v5 = bfu(xs[c5 * SB + lane]);
            const float v6 = bfu(xs[c6 * SB + lane]);
            const float v7 = bfu(xs[c7 * SB + lane]);

            const float haa = gate1(smc[g*7 + 0], v0, v1);
            const float hab = gate1(smc[g*7 + 1], v2, v3);
            const float hba = gate1(smc[g*7 + 2], v4, v5);
            const float hbb = gate1(smc[g*7 + 3], v6, v7);
            const float h2a = gate1(smc[g*7 + 4], haa, hab);
            const float h2b = gate1(smc[g*7 + 5], hba, hbb);
            const float h3  = gate1(smc[g*7 + 6], h2a, h2b);

            const int gl = ci * MCH + g;            // wave-uniform
            if (gl < split) acc0 += h3; else acc1 += h3;
        }
    }

    // ---- block reduction + grouped atomic add
    sred[wave][lane] = make_float2(acc0, acc1);
    __syncthreads();
    if (wave == 0) {
        float t0 = 0.f, t1 = 0.f;
        #pragma unroll
        for (int w = 0; w < NWAVE; ++w) {
            const float2 q = sred[w][lane];
            t0 += q.x; t1 += q.y;
        }
        const float sc = 1.0f / TAU;
        const int b = slice * SB + lane;            // batch elem
        atomicAdd(&red_out[b * NGROUP + grp0], t0 * sc);
        if (split < GPB2)
            atomicAdd(&red_out[b * NGROUP + grp0 + 1], t1 * sc);
    }
}

// ---------------------------------------------------------------- launch
extern "C" void kernel_launch(void* const* d_in, const int* in_sizes, int n_in,
                              void* d_out, int out_size, void* d_ws, size_t ws_size,
                              hipStream_t stream)
{
    const float* x   = (const float*)d_in[0];
    const float* w1  = (const float*)d_in[1];
    const float* w2  = (const float*)d_in[2];
    const float* w3  = (const float*)d_in[3];
    const int*   ia1 = (const int*)d_in[4];
    const int*   ib1 = (const int*)d_in[5];
    const int*   ia2 = (const int*)d_in[6];
    const int*   ib2 = (const int*)d_in[7];
    const int*   ia3 = (const int*)d_in[8];
    const int*   ib3 = (const int*)d_in[9];
    float* out = (float*)d_out;

    // workspace: xT (0.5MB) | leaf (2MB) | pc (7MB) | c1,c2,c3 (3MB) ~= 12.5MB
    char* ws = (char*)d_ws;
    ushort_t* xT = (ushort_t*)ws;
    int*    leaf = (int*)(ws + (size_t)IN_DIM * BATCH * 2);
    float4*   pc = (float4*)(leaf + (size_t)WIDTH * 8);
    float4*   c1 = pc + (size_t)WIDTH * 7;
    float4*   c2 = c1 + WIDTH;
    float4*   c3 = c2 + WIDTH;

    hipMemsetAsync(d_out, 0, (size_t)out_size * sizeof(float), stream);

    transpose_kernel<<<64, 256, 0, stream>>>(x, xT);
    coef_kernel<<<(3 * WIDTH) / 256, 256, 0, stream>>>(w1, w2, w3, c1, c2, c3);
    prep_kernel<<<WIDTH / 256, 256, 0, stream>>>(ia1, ib1, ia2, ib2, ia3, ib3,
                                                 c1, c2, c3, leaf, pc);
    fused_kernel<<<NBLK, 1024, 0, stream>>>(xT, leaf, pc, out);
}

// Round 8
// 132.806 us; speedup vs baseline: 3.1232x; 1.0765x over previous
//
#include <hip/hip_runtime.h>
#include <stdint.h>

// DiffLogic: 3-layer differentiable logic network.
// Round 14: R13 is spill-free and correct but instruction-bound: 17 DS ops +
// ~40 VALU per gate-eval, only 8 DS of which (data reads) are essential.
// Move ALL per-gate metadata (8 leaf idx + 7 coef float4 = 36 dwords) to the
// SCALAR pipe: wave-uniform gate index (readfirstlane) -> uniform loads ->
// s_load into SGPRs. Deletes the LDS metadata staging, its 8 barriers/block,
// 9 uniform ds_read_b128 and 8 v_readfirstlane per gate. Geometry bonus:
// 32 | 6400 -> a wave's 32-gate range never straddles a group boundary ->
// single accumulator, no per-gate select.
// LDS = xs(128K) + sred(8K) = 136KB; 1024 thr, 4 waves/SIMD as R13.

#define BATCH   256
#define IN_DIM  1024
#define WIDTH   64000
#define NGROUP  10
#define GSIZE   6400      // WIDTH / NGROUP
#define TAU     30.0f
#define NWAVE   16        // waves per block (1024 threads)
#define SLICES  4
#define SB      64        // batch elems per slice
#define GPB2    512       // gates per block
#define GPW2    (GPB2/NWAVE)   // 32 gates per wave, contiguous
#define NCHUNK  (WIDTH/GPB2)   // 125
#define NBLK    (NCHUNK*SLICES) // 500

typedef unsigned short ushort_t;

static __device__ __forceinline__ ushort_t f2bf(float f) {   // RNE
    uint32_t u = __float_as_uint(f);
    return (ushort_t)((u + 0x7fffu + ((u >> 16) & 1u)) >> 16);
}
static __device__ __forceinline__ float bfu(ushort_t s) {    // bf16 -> f32
    return __uint_as_float((uint32_t)s << 16);
}
// h = c0 + c1*a + c2*b + c3*(a*b) = b*(c3*a+c2) + (c1*a+c0)  -- 3 FMA
static __device__ __forceinline__ float gate1(float4 c, float a, float b) {
    return fmaf(b, fmaf(c.w, a, c.z), fmaf(c.y, a, c.x));
}

// ---------------------------------------------------------------- transpose
// x:(256,1024) f32 row-major -> xT:(1024,256) bf16
__global__ __launch_bounds__(256) void transpose_kernel(
    const float* __restrict__ x, ushort_t* __restrict__ xT)
{
    __shared__ float tile[64][65];
    const int c0 = (blockIdx.x & 15) * 64;
    const int b0 = (blockIdx.x >> 4) * 64;
    const int lt = threadIdx.x & 63;
    const int wt = threadIdx.x >> 6;
    for (int r = wt; r < 64; r += 4)
        tile[r][lt] = x[(b0 + r) * IN_DIM + c0 + lt];
    __syncthreads();
    for (int r = wt; r < 64; r += 4)
        xT[(c0 + r) * BATCH + b0 + lt] = f2bf(tile[lt][r]);
}

// ---------------------------------------------------------------- coefficients
__global__ __launch_bounds__(256) void coef_kernel(
    const float* __restrict__ w1, const float* __restrict__ w2,
    const float* __restrict__ w3,
    float4* __restrict__ c1o, float4* __restrict__ c2o, float4* __restrict__ c3o)
{
    const int id = blockIdx.x * 256 + threadIdx.x;
    const int layer = id / WIDTH;
    const int j = id - layer * WIDTH;
    const float* w = (layer == 0) ? w1 : (layer == 1) ? w2 : w3;
    float4* cc     = (layer == 0) ? c1o : (layer == 1) ? c2o : c3o;

    const float4* w4 = (const float4*)(w + (size_t)j * 16);
    float4 q0 = w4[0], q1 = w4[1], q2 = w4[2], q3 = w4[3];
    float p[16] = {q0.x,q0.y,q0.z,q0.w, q1.x,q1.y,q1.z,q1.w,
                   q2.x,q2.y,q2.z,q2.w, q3.x,q3.y,q3.z,q3.w};
    float m = p[0];
    #pragma unroll
    for (int i = 1; i < 16; ++i) m = fmaxf(m, p[i]);
    float s = 0.f;
    #pragma unroll
    for (int i = 0; i < 16; ++i) { p[i] = __expf(p[i] - m); s += p[i]; }
    const float inv = 1.0f / s;
    float c0 = (p[8]+p[9]+p[10]+p[11]+p[12]+p[13]+p[14]+p[15]) * inv;
    float c1 = (p[2]+p[3]+p[6]+p[7] - p[8]-p[9]-p[12]-p[13]) * inv;
    float c2 = (p[4]+p[5]+p[6]+p[7] - p[8]-p[9]-p[10]-p[11]) * inv;
    float c3 = (p[1]-p[2]-p[4]-2.f*p[6]-p[7]+p[8]+2.f*p[9]+p[11]+p[13]-p[14]) * inv;
    cc[j] = make_float4(c0, c1, c2, c3);
}

// ---------------------------------------------------------------- tree prep
__global__ __launch_bounds__(256) void prep_kernel(
    const int* __restrict__ ia1, const int* __restrict__ ib1,
    const int* __restrict__ ia2, const int* __restrict__ ib2,
    const int* __restrict__ ia3, const int* __restrict__ ib3,
    const float4* __restrict__ c1, const float4* __restrict__ c2,
    const float4* __restrict__ c3,
    int* __restrict__ leaf,        // [WIDTH][8]
    float4* __restrict__ pc)       // [WIDTH][7]
{
    const int j = blockIdx.x * 256 + threadIdx.x;
    if (j >= WIDTH) return;

    const int pa = ia3[j], pb = ib3[j];
    const int qaa = ia2[pa], qab = ib2[pa];
    const int qba = ia2[pb], qbb = ib2[pb];

    int* L = leaf + (size_t)j * 8;
    L[0] = ia1[qaa]; L[1] = ib1[qaa];
    L[2] = ia1[qab]; L[3] = ib1[qab];
    L[4] = ia1[qba]; L[5] = ib1[qba];
    L[6] = ia1[qbb]; L[7] = ib1[qbb];

    float4* P = pc + (size_t)j * 7;
    P[0] = c1[qaa]; P[1] = c1[qab]; P[2] = c1[qba]; P[3] = c1[qbb];
    P[4] = c2[pa];  P[5] = c2[pb];
    P[6] = c3[j];
}

// ---------------------------------------------------------------- fused net
__global__ __launch_bounds__(1024, 4) void fused_kernel(
    const ushort_t* __restrict__ xT,
    const int*      __restrict__ leaf,
    const float4*   __restrict__ pc,
    float*          __restrict__ red_out)
{
    __shared__ ushort_t xs[IN_DIM * SB];     // 128 KB  x-slice
    __shared__ float2   sred[NWAVE][64];     // 8 KB    reduction

    const int tid   = threadIdx.x;
    const int lane  = tid & 63;
    const int chunk = blockIdx.x >> 2;       // 0..124
    const int slice = blockIdx.x & 3;        // 0..3

    // ---- stage x slice (1024 cols x 64 batch, bf16): 128 B per thread
    {
        const int sub = tid & 15;            // 16 x 8B = one 128B row
        const int r0  = tid >> 4;            // 64 rows per pass
        for (int p = 0; p < 16; ++p) {
            const int row = p * 64 + r0;
            const uint2 v = *(const uint2*)(xT + (size_t)row * BATCH + slice * SB + sub * 4);
            *(uint2*)(xs + row * SB + sub * 4) = v;
        }
    }
    __syncthreads();

    const int gate0 = chunk * GPB2;                 // block's first gate
    const int grp0  = gate0 / GSIZE;
    const int split = (grp0 + 1) * GSIZE - gate0;   // local gates in grp0

    // wave-uniform gate range: metadata loads become s_load (scalar pipe)
    const int wu  = __builtin_amdgcn_readfirstlane(tid >> 6);
    const int gl0 = wu * GPW2;                      // wave's first local gate
    const int gw0 = gate0 + gl0;

    float acc = 0.f;

    #pragma unroll 2
    for (int i = 0; i < GPW2; ++i) {
        const int g = gw0 + i;                      // uniform
        const int4 iA = *(const int4*)(leaf + (size_t)g * 8);       // s_load
        const int4 iB = *(const int4*)(leaf + (size_t)g * 8 + 4);   // s_load
        const float4 K0 = pc[(size_t)g * 7 + 0];                    // s_load
        const float4 K1 = pc[(size_t)g * 7 + 1];
        const float4 K2 = pc[(size_t)g * 7 + 2];
        const float4 K3 = pc[(size_t)g * 7 + 3];
        const float4 K4 = pc[(size_t)g * 7 + 4];
        const float4 K5 = pc[(size_t)g * 7 + 5];
        const float4 K6 = pc[(size_t)g * 7 + 6];

        const float v0 = bfu(xs[iA.x * SB + lane]);
        const float v1 = bfu(xs[iA.y * SB + lane]);
        const float v2 = bfu(xs[iA.z * SB + lane]);
        const float v3 = bfu(xs[iA.w * SB + lane]);
        const float v4 = bfu(xs[iB.x * SB + lane]);
        const float v5 = bfu(xs[iB.y * SB + lane]);
        const float v6 = bfu(xs[iB.z * SB + lane]);
        const float v7 = bfu(xs[iB.w * SB + lane]);

        const float haa = gate1(K0, v0, v1);
        const float hab = gate1(K1, v2, v3);
        const float hba = gate1(K2, v4, v5);
        const float hbb = gate1(K3, v6, v7);
        const float h2a = gate1(K4, haa, hab);
        const float h2b = gate1(K5, hba, hbb);
        acc += gate1(K6, h2a, h2b);
    }

    // 32 | 6400 -> whole wave is in one group; uniform flag picks the slot
    const int inG1 = (gl0 >= split) ? 1 : 0;
    sred[wu][lane] = inG1 ? make_float2(0.f, acc) : make_float2(acc, 0.f);
    __syncthreads();
    if (wu == 0) {
        float t0 = 0.f, t1 = 0.f;
        #pragma unroll
        for (int w = 0; w < NWAVE; ++w) {
            const float2 q = sred[w][lane];
            t0 += q.x; t1 += q.y;
        }
        const float sc = 1.0f / TAU;
        const int b = slice * SB + lane;            // batch elem
        atomicAdd(&red_out[b * NGROUP + grp0], t0 * sc);
        if (split < GPB2)
            atomicAdd(&red_out[b * NGROUP + grp0 + 1], t1 * sc);
    }
}

// ---------------------------------------------------------------- launch
extern "C" void kernel_launch(void* const* d_in, const int* in_sizes, int n_in,
                              void* d_out, int out_size, void* d_ws, size_t ws_size,
                              hipStream_t stream)
{
    const float* x   = (const float*)d_in[0];
    const float* w1  = (const float*)d_in[1];
    const float* w2  = (const float*)d_in[2];
    const float* w3  = (const float*)d_in[3];
    const int*   ia1 = (const int*)d_in[4];
    const int*   ib1 = (const int*)d_in[5];
    const int*   ia2 = (const int*)d_in[6];
    const int*   ib2 = (const int*)d_in[7];
    const int*   ia3 = (const int*)d_in[8];
    const int*   ib3 = (const int*)d_in[9];
    float* out = (float*)d_out;

    // workspace: xT (0.5MB) | leaf (2MB) | pc (7MB) | c1,c2,c3 (3MB) ~= 12.5MB
    char* ws = (char*)d_ws;
    ushort_t* xT = (ushort_t*)ws;
    int*    leaf = (int*)(ws + (size_t)IN_DIM * BATCH * 2);
    float4*   pc = (float4*)(leaf + (size_t)WIDTH * 8);
    float4*   c1 = pc + (size_t)WIDTH * 7;
    float4*   c2 = c1 + WIDTH;
    float4*   c3 = c2 + WIDTH;

    hipMemsetAsync(d_out, 0, (size_t)out_size * sizeof(float), stream);

    transpose_kernel<<<64, 256, 0, stream>>>(x, xT);
    coef_kernel<<<(3 * WIDTH) / 256, 256, 0, stream>>>(w1, w2, w3, c1, c2, c3);
    prep_kernel<<<WIDTH / 256, 256, 0, stream>>>(ia1, ib1, ia2, ib2, ia3, ib3,
                                                 c1, c2, c3, leaf, pc);
    fused_kernel<<<NBLK, 1024, 0, stream>>>(xT, leaf, pc, out);
}

// Round 9
// 128.473 us; speedup vs baseline: 3.2285x; 1.0337x over previous
//
#include <hip/hip_runtime.h>
#include <stdint.h>

// DiffLogic: 3-layer differentiable logic network.
// Round 15: drop the LDS x-slice. With metadata on the scalar pipe (R14),
// the global-gather form dominates: lane holds ushort4 = 4 batch elems ->
// one wave covers the FULL 256 batch -> 64K wave-gate-evals (was 256K with
// 4 slices), metadata SMEM 9.2MB (was 36.9), ZERO DS ops in the loop, and
// gathers are saddr-form (SGPR col base + constant lane voffset) from the
// 0.5MB L2-resident xT. LDS = 16KB reduction only -> grid 250x1024, one
// pass, no group straddle (256 | 6400). Spill discipline: named uint2
// locals consumed in-iteration, unroll 2, launch_bounds(1024,4).

#define BATCH   256
#define IN_DIM  1024
#define WIDTH   64000
#define NGROUP  10
#define GSIZE   6400      // WIDTH / NGROUP
#define TAU     30.0f
#define NWAVE   16        // waves per block (1024 threads)
#define GPB3    256       // gates per block; 6400 % 256 == 0 -> no straddle
#define GPW3    (GPB3/NWAVE)   // 16 gates per wave
#define NBLK3   (WIDTH/GPB3)   // 250 blocks -> single pass on 256 CUs
#define BPG     (GSIZE/GPB3)   // 25 blocks per output group

typedef unsigned short ushort_t;

static __device__ __forceinline__ ushort_t f2bf(float f) {   // RNE
    uint32_t u = __float_as_uint(f);
    return (ushort_t)((u + 0x7fffu + ((u >> 16) & 1u)) >> 16);
}
static __device__ __forceinline__ float bfl(uint32_t u) {    // low bf16 -> f32
    return __uint_as_float(u << 16);
}
static __device__ __forceinline__ float bfh(uint32_t u) {    // high bf16 -> f32
    return __uint_as_float(u & 0xffff0000u);
}
// h = c0 + c1*a + c2*b + c3*(a*b) = b*(c3*a+c2) + (c1*a+c0)  -- 3 FMA
static __device__ __forceinline__ float gate1(float4 c, float a, float b) {
    return fmaf(b, fmaf(c.w, a, c.z), fmaf(c.y, a, c.x));
}
static __device__ __forceinline__ float4 gate4(float4 c, float4 a, float4 b) {
    float4 r;
    r.x = gate1(c, a.x, b.x);
    r.y = gate1(c, a.y, b.y);
    r.z = gate1(c, a.z, b.z);
    r.w = gate1(c, a.w, b.w);
    return r;
}
// packed inputs: a,b are uint2 holding 4 bf16 batch elems each
static __device__ __forceinline__ float4 gate4u(float4 c, uint2 a, uint2 b) {
    float4 r;
    r.x = gate1(c, bfl(a.x), bfl(b.x));
    r.y = gate1(c, bfh(a.x), bfh(b.x));
    r.z = gate1(c, bfl(a.y), bfl(b.y));
    r.w = gate1(c, bfh(a.y), bfh(b.y));
    return r;
}

// ---------------------------------------------------------------- transpose
// x:(256,1024) f32 row-major -> xT:(1024,256) bf16
__global__ __launch_bounds__(256) void transpose_kernel(
    const float* __restrict__ x, ushort_t* __restrict__ xT)
{
    __shared__ float tile[64][65];
    const int c0 = (blockIdx.x & 15) * 64;
    const int b0 = (blockIdx.x >> 4) * 64;
    const int lt = threadIdx.x & 63;
    const int wt = threadIdx.x >> 6;
    for (int r = wt; r < 64; r += 4)
        tile[r][lt] = x[(b0 + r) * IN_DIM + c0 + lt];
    __syncthreads();
    for (int r = wt; r < 64; r += 4)
        xT[(c0 + r) * BATCH + b0 + lt] = f2bf(tile[lt][r]);
}

// ---------------------------------------------------------------- coefficients
__global__ __launch_bounds__(256) void coef_kernel(
    const float* __restrict__ w1, const float* __restrict__ w2,
    const float* __restrict__ w3,
    float4* __restrict__ c1o, float4* __restrict__ c2o, float4* __restrict__ c3o)
{
    const int id = blockIdx.x * 256 + threadIdx.x;
    const int layer = id / WIDTH;
    const int j = id - layer * WIDTH;
    const float* w = (layer == 0) ? w1 : (layer == 1) ? w2 : w3;
    float4* cc     = (layer == 0) ? c1o : (layer == 1) ? c2o : c3o;

    const float4* w4 = (const float4*)(w + (size_t)j * 16);
    float4 q0 = w4[0], q1 = w4[1], q2 = w4[2], q3 = w4[3];
    float p[16] = {q0.x,q0.y,q0.z,q0.w, q1.x,q1.y,q1.z,q1.w,
                   q2.x,q2.y,q2.z,q2.w, q3.x,q3.y,q3.z,q3.w};
    float m = p[0];
    #pragma unroll
    for (int i = 1; i < 16; ++i) m = fmaxf(m, p[i]);
    float s = 0.f;
    #pragma unroll
    for (int i = 0; i < 16; ++i) { p[i] = __expf(p[i] - m); s += p[i]; }
    const float inv = 1.0f / s;
    float c0 = (p[8]+p[9]+p[10]+p[11]+p[12]+p[13]+p[14]+p[15]) * inv;
    float c1 = (p[2]+p[3]+p[6]+p[7] - p[8]-p[9]-p[12]-p[13]) * inv;
    float c2 = (p[4]+p[5]+p[6]+p[7] - p[8]-p[9]-p[10]-p[11]) * inv;
    float c3 = (p[1]-p[2]-p[4]-2.f*p[6]-p[7]+p[8]+2.f*p[9]+p[11]+p[13]-p[14]) * inv;
    cc[j] = make_float4(c0, c1, c2, c3);
}

// ---------------------------------------------------------------- tree prep
// One thread per final gate j: flatten its depth-3 tree into a single
// 36-dword record: [iA(4) | iB(4) | K0..K6(28)] -> 3 s_loads in the hot loop.
__global__ __launch_bounds__(256) void prep_kernel(
    const int* __restrict__ ia1, const int* __restrict__ ib1,
    const int* __restrict__ ia2, const int* __restrict__ ib2,
    const int* __restrict__ ia3, const int* __restrict__ ib3,
    const float4* __restrict__ c1, const float4* __restrict__ c2,
    const float4* __restrict__ c3,
    int* __restrict__ meta)        // [WIDTH][36]
{
    const int j = blockIdx.x * 256 + threadIdx.x;
    if (j >= WIDTH) return;

    const int pa = ia3[j], pb = ib3[j];
    const int qaa = ia2[pa], qab = ib2[pa];
    const int qba = ia2[pb], qbb = ib2[pb];

    int* M = meta + (size_t)j * 36;
    M[0] = ia1[qaa]; M[1] = ib1[qaa];
    M[2] = ia1[qab]; M[3] = ib1[qab];
    M[4] = ia1[qba]; M[5] = ib1[qba];
    M[6] = ia1[qbb]; M[7] = ib1[qbb];

    float4* P = (float4*)(M + 8);
    P[0] = c1[qaa]; P[1] = c1[qab]; P[2] = c1[qba]; P[3] = c1[qbb];
    P[4] = c2[pa];  P[5] = c2[pb];
    P[6] = c3[j];
}

// ---------------------------------------------------------------- fused net
__global__ __launch_bounds__(1024, 4) void fused_kernel(
    const ushort_t* __restrict__ xT,
    const int*      __restrict__ meta,
    float*          __restrict__ red_out)
{
    __shared__ float4 sred[NWAVE][64];       // 16 KB

    const int tid  = threadIdx.x;
    const int lane = tid & 63;
    const int wu   = __builtin_amdgcn_readfirstlane(tid >> 6);
    const int g0   = blockIdx.x * GPB3 + wu * GPW3;   // uniform

    float4 acc = make_float4(0.f, 0.f, 0.f, 0.f);

    #pragma unroll 2
    for (int i = 0; i < GPW3; ++i) {
        const int g = g0 + i;                         // uniform
        const int* mp = meta + (size_t)g * 36;        // -> s_load
        const int4 iA   = *(const int4*)(mp);
        const int4 iB   = *(const int4*)(mp + 4);
        const float4 K0 = *(const float4*)(mp + 8);
        const float4 K1 = *(const float4*)(mp + 12);
        const float4 K2 = *(const float4*)(mp + 16);
        const float4 K3 = *(const float4*)(mp + 20);
        const float4 K4 = *(const float4*)(mp + 24);
        const float4 K5 = *(const float4*)(mp + 28);
        const float4 K6 = *(const float4*)(mp + 32);

        // 8 saddr-form gathers: SGPR col base + lane*8 voffset, L2-resident
        const uint2 q0 = ((const uint2*)(xT + (size_t)iA.x * BATCH))[lane];
        const uint2 q1 = ((const uint2*)(xT + (size_t)iA.y * BATCH))[lane];
        const uint2 q2 = ((const uint2*)(xT + (size_t)iA.z * BATCH))[lane];
        const uint2 q3 = ((const uint2*)(xT + (size_t)iA.w * BATCH))[lane];
        const uint2 q4 = ((const uint2*)(xT + (size_t)iB.x * BATCH))[lane];
        const uint2 q5 = ((const uint2*)(xT + (size_t)iB.y * BATCH))[lane];
        const uint2 q6 = ((const uint2*)(xT + (size_t)iB.z * BATCH))[lane];
        const uint2 q7 = ((const uint2*)(xT + (size_t)iB.w * BATCH))[lane];

        const float4 haa = gate4u(K0, q0, q1);
        const float4 hab = gate4u(K1, q2, q3);
        const float4 hba = gate4u(K2, q4, q5);
        const float4 hbb = gate4u(K3, q6, q7);
        const float4 h2a = gate4(K4, haa, hab);
        const float4 h2b = gate4(K5, hba, hbb);
        const float4 h3  = gate4(K6, h2a, h2b);
        acc.x += h3.x; acc.y += h3.y; acc.z += h3.z; acc.w += h3.w;
    }

    // ---- block reduction + grouped atomic add (block fully inside a group)
    sred[wu][lane] = acc;
    __syncthreads();
    if (wu == 0) {
        float4 t = sred[0][lane];
        #pragma unroll
        for (int w = 1; w < NWAVE; ++w) {
            float4 q = sred[w][lane];
            t.x += q.x; t.y += q.y; t.z += q.z; t.w += q.w;
        }
        const float sc = 1.0f / TAU;
        const int grp = blockIdx.x / BPG;
        const int b0 = lane * 4;
        atomicAdd(&red_out[(b0 + 0) * NGROUP + grp], t.x * sc);
        atomicAdd(&red_out[(b0 + 1) * NGROUP + grp], t.y * sc);
        atomicAdd(&red_out[(b0 + 2) * NGROUP + grp], t.z * sc);
        atomicAdd(&red_out[(b0 + 3) * NGROUP + grp], t.w * sc);
    }
}

// ---------------------------------------------------------------- launch
extern "C" void kernel_launch(void* const* d_in, const int* in_sizes, int n_in,
                              void* d_out, int out_size, void* d_ws, size_t ws_size,
                              hipStream_t stream)
{
    const float* x   = (const float*)d_in[0];
    const float* w1  = (const float*)d_in[1];
    const float* w2  = (const float*)d_in[2];
    const float* w3  = (const float*)d_in[3];
    const int*   ia1 = (const int*)d_in[4];
    const int*   ib1 = (const int*)d_in[5];
    const int*   ia2 = (const int*)d_in[6];
    const int*   ib2 = (const int*)d_in[7];
    const int*   ia3 = (const int*)d_in[8];
    const int*   ib3 = (const int*)d_in[9];
    float* out = (float*)d_out;

    // workspace: xT (0.5MB) | meta (9.2MB) | c1,c2,c3 (3MB) ~= 12.7MB
    char* ws = (char*)d_ws;
    ushort_t* xT = (ushort_t*)ws;
    int*    meta = (int*)(ws + (size_t)IN_DIM * BATCH * 2);
    float4*   c1 = (float4*)(meta + (size_t)WIDTH * 36);
    float4*   c2 = c1 + WIDTH;
    float4*   c3 = c2 + WIDTH;

    hipMemsetAsync(d_out, 0, (size_t)out_size * sizeof(float), stream);

    transpose_kernel<<<64, 256, 0, stream>>>(x, xT);
    coef_kernel<<<(3 * WIDTH) / 256, 256, 0, stream>>>(w1, w2, w3, c1, c2, c3);
    prep_kernel<<<WIDTH / 256, 256, 0, stream>>>(ia1, ib1, ia2, ib2, ia3, ib3,
                                                 c1, c2, c3, meta);
    fused_kernel<<<NBLK3, 1024, 0, stream>>>(xT, meta, out);
}